// Round 1
// baseline (1719.753 us; speedup 1.0000x reference)
//
#include <hip/hip_runtime.h>
#include <hip/hip_bf16.h>
#include <stdint.h>

// Problem constants (DeepSeekV3 MoE: B=4,S=2048,H=2048, I=1408, E=16, K=2)
#define T_TOK 8192
#define H_DIM 2048
#define I_DIM 1408
#define E_NUM 16

typedef __hip_bfloat16 bf16;
typedef __bf16 bf16x8 __attribute__((ext_vector_type(8)));
typedef float f32x4 __attribute__((ext_vector_type(4)));

// meta[] int layout in ws
#define M_CNT 0    // counts[16]
#define M_OFF 16   // offsets[17]
#define M_CUR 33   // cursors[16]
#define M_WLC 49   // worklist count
#define M_WLE 64   // wl expert id [160]
#define M_WLM 224  // wl m-tile idx [160]

#define GLOAD_LDS16(g, l)                                                          \
  __builtin_amdgcn_global_load_lds(                                               \
      (const __attribute__((address_space(1))) void*)(g),                         \
      (__attribute__((address_space(3))) void*)(l), 16, 0, 0)

// ---------------------------------------------------------------- zero meta
__global__ void zero_meta_kernel(int* __restrict__ meta) {
  for (int i = threadIdx.x; i < 1024; i += 256) meta[i] = 0;
}

// ---------------------------------------------------------------- fp32 -> bf16
__global__ void cvt_kernel(const float* __restrict__ src, bf16* __restrict__ dst, long n) {
  long i = ((long)blockIdx.x * 256 + threadIdx.x) * 4;
  const long stride = (long)gridDim.x * 256 * 4;
  for (; i < n; i += stride) {
    const float4 v = *reinterpret_cast<const float4*>(src + i);
    union { bf16 b[4]; ushort4 u; } o;
    o.b[0] = __float2bfloat16(v.x);
    o.b[1] = __float2bfloat16(v.y);
    o.b[2] = __float2bfloat16(v.z);
    o.b[3] = __float2bfloat16(v.w);
    *reinterpret_cast<ushort4*>(dst + i) = o.u;
  }
}

// ---------------------------------------------------------------- gating
// one wave per token: fp32 logits, sigmoid, bias-corrected top-2, normalized gates
__global__ __launch_bounds__(256) void gate_kernel(
    const float* __restrict__ X, const float* __restrict__ GW,
    const float* __restrict__ bias, int* __restrict__ topk_idx,
    float* __restrict__ topk_gate, int* __restrict__ meta) {
  const int lane = threadIdx.x & 63;
  const int t = blockIdx.x * 4 + (threadIdx.x >> 6);
  const float* xr = X + (size_t)t * H_DIM;
  float acc[E_NUM];
#pragma unroll
  for (int e = 0; e < E_NUM; ++e) acc[e] = 0.f;
  for (int h = lane; h < H_DIM; h += 64) {
    const float xv = xr[h];
#pragma unroll
    for (int e = 0; e < E_NUM; ++e) acc[e] += xv * GW[e * H_DIM + h];
  }
#pragma unroll
  for (int o = 32; o > 0; o >>= 1) {
#pragma unroll
    for (int e = 0; e < E_NUM; ++e) acc[e] += __shfl_xor(acc[e], o);
  }
  if (lane == 0) {
    float s[E_NUM], r[E_NUM];
#pragma unroll
    for (int e = 0; e < E_NUM; ++e) {
      s[e] = 1.f / (1.f + expf(-acc[e]));
      r[e] = s[e] + bias[e];
    }
    int i1 = 0;
    for (int e = 1; e < E_NUM; ++e) if (r[e] > r[i1]) i1 = e;
    int i2 = (i1 == 0) ? 1 : 0;
    for (int e = 0; e < E_NUM; ++e) if (e != i1 && r[e] > r[i2]) i2 = e;
    const float g1 = s[i1], g2 = s[i2];
    const float inv = 1.f / (g1 + g2);
    topk_idx[2 * t] = i1;
    topk_idx[2 * t + 1] = i2;
    topk_gate[2 * t] = g1 * inv;
    topk_gate[2 * t + 1] = g2 * inv;
    atomicAdd(&meta[M_CNT + i1], 1);
    atomicAdd(&meta[M_CNT + i2], 1);
  }
}

// ---------------------------------------------------------------- scan + worklist
__global__ void scan_kernel(int* __restrict__ meta) {
  if (threadIdx.x == 0) {
    int off = 0, nw = 0;
    for (int e = 0; e < E_NUM; ++e) {
      meta[M_OFF + e] = off;
      const int c = meta[M_CNT + e];
      const int nt = (c + 127) >> 7;
      for (int i = 0; i < nt; ++i) { meta[M_WLE + nw] = e; meta[M_WLM + nw] = i; ++nw; }
      off += c;
      meta[M_CUR + e] = 0;
    }
    meta[M_OFF + 16] = off;
    meta[M_WLC] = nw;
  }
}

// ---------------------------------------------------------------- scatter tokens into expert lists
__global__ void scatter_kernel(const int* __restrict__ topk_idx,
                               const float* __restrict__ topk_gate,
                               int* __restrict__ meta, int* __restrict__ list_token,
                               float* __restrict__ list_gate) {
  const int t = blockIdx.x * 256 + threadIdx.x;
#pragma unroll
  for (int k = 0; k < 2; ++k) {
    const int e = topk_idx[2 * t + k];
    const float g = topk_gate[2 * t + k];
    const int slot = atomicAdd(&meta[M_CUR + e], 1);
    const int p = meta[M_OFF + e] + slot;
    list_token[p] = t;
    list_gate[p] = g;
  }
}

// ---------------------------------------------------------------- dual GEMM (x@W1^T, x@W3^T) + silu-mul [+gate]
// 128x128 tile, BK=32, 4 waves each 64x64, mfma 16x16x32 bf16. Both A,B tiles [row][32] layout.
template <bool ROUTED>
__global__ __launch_bounds__(256, 2) void gemm1_dual_kernel(
    const bf16* __restrict__ X, const bf16* __restrict__ W1,
    const bf16* __restrict__ W3, bf16* __restrict__ Hout,
    const int* __restrict__ meta, const int* __restrict__ list_token,
    const float* __restrict__ list_gate) {
  __shared__ alignas(16) bf16 As[128 * 32];
  __shared__ alignas(16) bf16 B1s[128 * 32];
  __shared__ alignas(16) bf16 B3s[128 * 32];

  const int tid = threadIdx.x;
  const int lane = tid & 63;
  const int wid = tid >> 6;

  int mt, nt, nrows = T_TOK, rowbase = 0;
  const bf16 *w1p, *w3p;
  if constexpr (ROUTED) {
    if ((int)blockIdx.x >= meta[M_WLC]) return;
    const int e = meta[M_WLE + blockIdx.x];
    mt = meta[M_WLM + blockIdx.x];
    nt = blockIdx.y;
    rowbase = meta[M_OFF + e];
    nrows = meta[M_CNT + e];
    w1p = W1 + (size_t)e * I_DIM * H_DIM;
    w3p = W3 + (size_t)e * I_DIM * H_DIM;
  } else {
    mt = blockIdx.x;
    nt = blockIdx.y;
    w1p = W1;
    w3p = W3;
  }

  // staging: 512 chunks of 16B per tile; chunk c -> row c>>2, k-chunk c&3; thread stages c=tid, tid+256
  const int r0 = tid >> 2, r1 = (tid + 256) >> 2;
  const int kc0 = (tid & 3) * 8, kc1 = ((tid + 256) & 3) * 8;
  long arow0, arow1;
  if constexpr (ROUTED) {
    int s0 = mt * 128 + r0; if (s0 > nrows - 1) s0 = nrows - 1;
    int s1 = mt * 128 + r1; if (s1 > nrows - 1) s1 = nrows - 1;
    arow0 = list_token[rowbase + s0];
    arow1 = list_token[rowbase + s1];
  } else {
    arow0 = (long)mt * 128 + r0;
    arow1 = (long)mt * 128 + r1;
  }
  const long brow0 = (long)nt * 128 + r0;
  const long brow1 = (long)nt * 128 + r1;

  const bf16* ap0 = X + (size_t)arow0 * H_DIM + kc0;
  const bf16* ap1 = X + (size_t)arow1 * H_DIM + kc1;
  const bf16* b1p0 = w1p + (size_t)brow0 * H_DIM + kc0;
  const bf16* b1p1 = w1p + (size_t)brow1 * H_DIM + kc1;
  const bf16* b3p0 = w3p + (size_t)brow0 * H_DIM + kc0;
  const bf16* b3p1 = w3p + (size_t)brow1 * H_DIM + kc1;

  // wave-uniform LDS bases (chunk = wid*64 + lane, second set +256)
  bf16* As_w0 = As + wid * 512;
  bf16* As_w1 = As + 2048 + wid * 512;
  bf16* B1_w0 = B1s + wid * 512;
  bf16* B1_w1 = B1s + 2048 + wid * 512;
  bf16* B3_w0 = B3s + wid * 512;
  bf16* B3_w1 = B3s + 2048 + wid * 512;

  f32x4 acc1[4][4], acc3[4][4];
#pragma unroll
  for (int i = 0; i < 4; ++i)
#pragma unroll
    for (int j = 0; j < 4; ++j) {
      acc1[i][j] = (f32x4){0.f, 0.f, 0.f, 0.f};
      acc3[i][j] = (f32x4){0.f, 0.f, 0.f, 0.f};
    }

  const int wm = wid >> 1, wn = wid & 1;
  const int fr = lane & 15;
  const int kof = (lane >> 4) * 8;

  for (int kt = 0; kt < H_DIM / 32; ++kt) {
    const int k0 = kt * 32;
    GLOAD_LDS16(ap0 + k0, As_w0);
    GLOAD_LDS16(ap1 + k0, As_w1);
    GLOAD_LDS16(b1p0 + k0, B1_w0);
    GLOAD_LDS16(b1p1 + k0, B1_w1);
    GLOAD_LDS16(b3p0 + k0, B3_w0);
    GLOAD_LDS16(b3p1 + k0, B3_w1);
    __syncthreads();

    bf16x8 a[4], b1[4], b3[4];
#pragma unroll
    for (int mf = 0; mf < 4; ++mf)
      a[mf] = *reinterpret_cast<const bf16x8*>(&As[(wm * 64 + mf * 16 + fr) * 32 + kof]);
#pragma unroll
    for (int nf = 0; nf < 4; ++nf) {
      b1[nf] = *reinterpret_cast<const bf16x8*>(&B1s[(wn * 64 + nf * 16 + fr) * 32 + kof]);
      b3[nf] = *reinterpret_cast<const bf16x8*>(&B3s[(wn * 64 + nf * 16 + fr) * 32 + kof]);
    }
#pragma unroll
    for (int mf = 0; mf < 4; ++mf)
#pragma unroll
      for (int nf = 0; nf < 4; ++nf) {
        acc1[mf][nf] = __builtin_amdgcn_mfma_f32_16x16x32_bf16(a[mf], b1[nf], acc1[mf][nf], 0, 0, 0);
        acc3[mf][nf] = __builtin_amdgcn_mfma_f32_16x16x32_bf16(a[mf], b3[nf], acc3[mf][nf], 0, 0, 0);
      }
    __syncthreads();
  }

  // epilogue: h = silu(a1)*a3 [*gate], C/D map: col=lane&15, row=(lane>>4)*4+j
#pragma unroll
  for (int mf = 0; mf < 4; ++mf)
#pragma unroll
    for (int nf = 0; nf < 4; ++nf)
#pragma unroll
      for (int j = 0; j < 4; ++j) {
        const int rl = wm * 64 + mf * 16 + (lane >> 4) * 4 + j;
        const int col = nt * 128 + wn * 64 + nf * 16 + fr;
        const float z = acc1[mf][nf][j];
        float h = z / (1.f + expf(-z)) * acc3[mf][nf][j];
        if constexpr (ROUTED) {
          const int slot = mt * 128 + rl;
          if (slot < nrows) {
            h *= list_gate[rowbase + slot];
            Hout[(size_t)(rowbase + slot) * I_DIM + col] = __float2bfloat16(h);
          }
        } else {
          Hout[(size_t)(mt * 128 + rl) * I_DIM + col] = __float2bfloat16(h);
        }
      }
}

// ---------------------------------------------------------------- GEMM2: h @ W2^T -> out (fp32)
template <bool ROUTED>
__global__ __launch_bounds__(256, 2) void gemm2_kernel(
    const bf16* __restrict__ Hin, const bf16* __restrict__ W2,
    float* __restrict__ Out, const int* __restrict__ meta,
    const int* __restrict__ list_token) {
  __shared__ alignas(16) bf16 As[128 * 32];
  __shared__ alignas(16) bf16 Bs[128 * 32];

  const int tid = threadIdx.x;
  const int lane = tid & 63;
  const int wid = tid >> 6;

  int mt, nt, nrows = T_TOK, rowbase = 0;
  const bf16* w2p;
  if constexpr (ROUTED) {
    if ((int)blockIdx.x >= meta[M_WLC]) return;
    const int e = meta[M_WLE + blockIdx.x];
    mt = meta[M_WLM + blockIdx.x];
    nt = blockIdx.y;
    rowbase = meta[M_OFF + e];
    nrows = meta[M_CNT + e];
    w2p = W2 + (size_t)e * H_DIM * I_DIM;
  } else {
    mt = blockIdx.x;
    nt = blockIdx.y;
    w2p = W2;
  }

  const int r0 = tid >> 2, r1 = (tid + 256) >> 2;
  const int kc0 = (tid & 3) * 8, kc1 = ((tid + 256) & 3) * 8;
  const long arow0 = (long)rowbase + mt * 128 + r0;  // rowbase=0 when !ROUTED
  const long arow1 = (long)rowbase + mt * 128 + r1;
  const long brow0 = (long)nt * 128 + r0;
  const long brow1 = (long)nt * 128 + r1;

  const bf16* ap0 = Hin + (size_t)arow0 * I_DIM + kc0;
  const bf16* ap1 = Hin + (size_t)arow1 * I_DIM + kc1;
  const bf16* bp0 = w2p + (size_t)brow0 * I_DIM + kc0;
  const bf16* bp1 = w2p + (size_t)brow1 * I_DIM + kc1;

  bf16* As_w0 = As + wid * 512;
  bf16* As_w1 = As + 2048 + wid * 512;
  bf16* Bs_w0 = Bs + wid * 512;
  bf16* Bs_w1 = Bs + 2048 + wid * 512;

  f32x4 acc[4][4];
#pragma unroll
  for (int i = 0; i < 4; ++i)
#pragma unroll
    for (int j = 0; j < 4; ++j) acc[i][j] = (f32x4){0.f, 0.f, 0.f, 0.f};

  const int wm = wid >> 1, wn = wid & 1;
  const int fr = lane & 15;
  const int kof = (lane >> 4) * 8;

  for (int kt = 0; kt < I_DIM / 32; ++kt) {
    const int k0 = kt * 32;
    GLOAD_LDS16(ap0 + k0, As_w0);
    GLOAD_LDS16(ap1 + k0, As_w1);
    GLOAD_LDS16(bp0 + k0, Bs_w0);
    GLOAD_LDS16(bp1 + k0, Bs_w1);
    __syncthreads();

    bf16x8 a[4], b[4];
#pragma unroll
    for (int mf = 0; mf < 4; ++mf)
      a[mf] = *reinterpret_cast<const bf16x8*>(&As[(wm * 64 + mf * 16 + fr) * 32 + kof]);
#pragma unroll
    for (int nf = 0; nf < 4; ++nf)
      b[nf] = *reinterpret_cast<const bf16x8*>(&Bs[(wn * 64 + nf * 16 + fr) * 32 + kof]);
#pragma unroll
    for (int mf = 0; mf < 4; ++mf)
#pragma unroll
      for (int nf = 0; nf < 4; ++nf)
        acc[mf][nf] = __builtin_amdgcn_mfma_f32_16x16x32_bf16(a[mf], b[nf], acc[mf][nf], 0, 0, 0);
    __syncthreads();
  }

#pragma unroll
  for (int mf = 0; mf < 4; ++mf)
#pragma unroll
    for (int nf = 0; nf < 4; ++nf)
#pragma unroll
      for (int j = 0; j < 4; ++j) {
        const int rl = wm * 64 + mf * 16 + (lane >> 4) * 4 + j;
        const int col = nt * 128 + wn * 64 + nf * 16 + fr;
        const float v = acc[mf][nf][j];
        if constexpr (ROUTED) {
          const int slot = mt * 128 + rl;
          if (slot < nrows) {
            const int tok = list_token[rowbase + slot];
            atomicAdd(&Out[(size_t)tok * H_DIM + col], v);
          }
        } else {
          Out[(size_t)(mt * 128 + rl) * H_DIM + col] = v;
        }
      }
}

// ---------------------------------------------------------------- launch
extern "C" void kernel_launch(void* const* d_in, const int* in_sizes, int n_in,
                              void* d_out, int out_size, void* d_ws, size_t ws_size,
                              hipStream_t stream) {
  const float* x_f = (const float*)d_in[0];
  const float* gw_f = (const float*)d_in[1];
  const float* bias_f = (const float*)d_in[2];
  const float* sw1_f = (const float*)d_in[3];
  const float* sw3_f = (const float*)d_in[4];
  const float* sw2_f = (const float*)d_in[5];
  const float* w1_f = (const float*)d_in[6];
  const float* w3_f = (const float*)d_in[7];
  const float* w2_f = (const float*)d_in[8];
  float* out = (float*)d_out;

  char* ws = (char*)d_ws;
  size_t off = 0;
  auto alloc = [&](size_t bytes) {
    char* p = ws + off;
    off += (bytes + 255) & ~(size_t)255;
    return p;
  };

  bf16* x_bf = (bf16*)alloc((size_t)T_TOK * H_DIM * 2);
  bf16* sw1_bf = (bf16*)alloc((size_t)I_DIM * H_DIM * 2);
  bf16* sw3_bf = (bf16*)alloc((size_t)I_DIM * H_DIM * 2);
  bf16* sw2_bf = (bf16*)alloc((size_t)H_DIM * I_DIM * 2);
  bf16* w1_bf = (bf16*)alloc((size_t)E_NUM * I_DIM * H_DIM * 2);
  bf16* w3_bf = (bf16*)alloc((size_t)E_NUM * I_DIM * H_DIM * 2);
  bf16* w2_bf = (bf16*)alloc((size_t)E_NUM * H_DIM * I_DIM * 2);
  bf16* h_sh = (bf16*)alloc((size_t)T_TOK * I_DIM * 2);
  bf16* h_rt = (bf16*)alloc((size_t)(2 * T_TOK + 256) * I_DIM * 2);
  int* meta = (int*)alloc(4096);
  int* topk_idx = (int*)alloc((size_t)T_TOK * 2 * 4);
  float* topk_gate = (float*)alloc((size_t)T_TOK * 2 * 4);
  int* list_token = (int*)alloc((size_t)T_TOK * 2 * 4);
  float* list_gate = (float*)alloc((size_t)T_TOK * 2 * 4);

  if (off > ws_size) return;  // ws too small: leave poison (diagnosable signature)

  zero_meta_kernel<<<1, 256, 0, stream>>>(meta);

  auto cvt = [&](const float* s, bf16* d, long n) {
    int blocks = (int)((n / 4 + 255) / 256);
    if (blocks > 8192) blocks = 8192;
    cvt_kernel<<<blocks, 256, 0, stream>>>(s, d, n);
  };
  cvt(x_f, x_bf, (long)T_TOK * H_DIM);
  cvt(sw1_f, sw1_bf, (long)I_DIM * H_DIM);
  cvt(sw3_f, sw3_bf, (long)I_DIM * H_DIM);
  cvt(sw2_f, sw2_bf, (long)H_DIM * I_DIM);
  cvt(w1_f, w1_bf, (long)E_NUM * I_DIM * H_DIM);
  cvt(w3_f, w3_bf, (long)E_NUM * I_DIM * H_DIM);
  cvt(w2_f, w2_bf, (long)E_NUM * H_DIM * I_DIM);

  gate_kernel<<<T_TOK / 4, 256, 0, stream>>>(x_f, gw_f, bias_f, topk_idx, topk_gate, meta);
  scan_kernel<<<1, 64, 0, stream>>>(meta);
  scatter_kernel<<<T_TOK / 256, 256, 0, stream>>>(topk_idx, topk_gate, meta, list_token, list_gate);

  // shared expert
  gemm1_dual_kernel<false><<<dim3(64, I_DIM / 128), 256, 0, stream>>>(
      x_bf, sw1_bf, sw3_bf, h_sh, meta, nullptr, nullptr);
  gemm2_kernel<false><<<dim3(64, H_DIM / 128), 256, 0, stream>>>(
      h_sh, sw2_bf, out, meta, nullptr);

  // routed experts (worklist-driven, max 144 m-tiles)
  gemm1_dual_kernel<true><<<dim3(160, I_DIM / 128), 256, 0, stream>>>(
      x_bf, w1_bf, w3_bf, h_rt, meta, list_token, list_gate);
  gemm2_kernel<true><<<dim3(160, H_DIM / 128), 256, 0, stream>>>(
      h_rt, w2_bf, out, meta, list_token);
}